// Round 1
// baseline (646.331 us; speedup 1.0000x reference)
//
#include <hip/hip_runtime.h>
#include <hip/hip_bf16.h>
#include <math.h>

typedef __attribute__((ext_vector_type(8))) short short8;
typedef __attribute__((ext_vector_type(4))) float f32x4;

#define NTOK 2048
#define HID  2880
#define QKVD 5120
#define KOFF 4096
#define VOFF 4608
#define ATTD 4096   // N_HEADS*HEAD_DIM

__device__ __forceinline__ unsigned short f2bf(float f) {
  union { float f; unsigned int u; } v; v.f = f;
  unsigned int u = v.u;
  unsigned int r = (u + 0x7FFFu + ((u >> 16) & 1u)) >> 16;
  return (unsigned short)r;
}
__device__ __forceinline__ float bf2f(unsigned short h) {
  union { unsigned int u; float f; } v; v.u = ((unsigned int)h) << 16; return v.f;
}
__device__ __forceinline__ unsigned int pack2(float a, float b) {
  return (unsigned int)f2bf(a) | ((unsigned int)f2bf(b) << 16);
}

// ---------------- RoPE cos/sin table (YaRN) ----------------
__global__ void rope_table_kernel(float* __restrict__ ctab, float* __restrict__ stab) {
  int idx = blockIdx.x * 256 + threadIdx.x;
  if (idx >= NTOK * 32) return;
  int pos = idx >> 5, i = idx & 31;
  const double theta = 150000.0;
  const double two_pi = 6.283185307179586476925286766559;
  double freq = pow(theta, (double)i / 32.0);
  double interp = 1.0 / (32.0 * freq);
  double extrap = 1.0 / freq;
  double low  = 32.0 * log(4096.0 / (32.0 * two_pi)) / log(theta);
  double high = 32.0 * log(4096.0 / (1.0  * two_pi)) / log(theta);
  double ramp = ((double)i - low) / (high - low);
  ramp = ramp < 0.0 ? 0.0 : (ramp > 1.0 ? 1.0 : ramp);
  double maskv = 1.0 - ramp;
  double inv = interp * (1.0 - maskv) + extrap * maskv;
  double ang = (double)pos * inv;
  double conc = 0.1 * log(32.0) + 1.0;
  ctab[idx] = (float)(cos(ang) * conc);
  stab[idx] = (float)(sin(ang) * conc);
}

// ---------------- RMSNorm fp32 -> bf16 ----------------
__global__ __launch_bounds__(256) void rmsnorm_kernel(
    const float* __restrict__ x, const float* __restrict__ scale,
    unsigned short* __restrict__ t) {
  int row = blockIdx.x;
  const float* xr = x + (size_t)row * HID;
  float ss = 0.f;
  for (int c = threadIdx.x; c < HID; c += 256) { float v = xr[c]; ss += v * v; }
  #pragma unroll
  for (int m = 1; m < 64; m <<= 1) ss += __shfl_xor(ss, m);
  __shared__ float red[4];
  if ((threadIdx.x & 63) == 0) red[threadIdx.x >> 6] = ss;
  __syncthreads();
  float tot = red[0] + red[1] + red[2] + red[3];
  float rs = rsqrtf(tot / (float)HID + 1e-5f);
  for (int c = threadIdx.x; c < HID; c += 256)
    t[(size_t)row * HID + c] = f2bf(xr[c] * rs * scale[c]);
}

// ---------------- GEMM: C[M,N] = A(bf16 MxK) @ B(fp32 NxK)^T + bias (+resid) ----------------
template<bool RESID>
__global__ __launch_bounds__(256) void gemm_kernel(
    const unsigned short* __restrict__ A, const float* __restrict__ B,
    const float* __restrict__ bias, const float* __restrict__ resid,
    float* __restrict__ C, int M, int N, int K) {
  __shared__ unsigned short sA[128][40];   // +8 pad: 2-way banks only
  __shared__ unsigned short sB[128][40];
  const int m0 = blockIdx.x * 128;
  const int n0 = blockIdx.y * 128;
  const int tid = threadIdx.x;
  const int lane = tid & 63;
  const int wid = tid >> 6;
  const int wm = (wid >> 1) * 64;
  const int wn = (wid & 1) * 64;
  const int fr = lane & 15;
  const int fc = (lane >> 4) * 8;

  f32x4 acc[4][4] = {};

  for (int k0 = 0; k0 < K; k0 += 32) {
    // stage A: 128x32 bf16, 16B chunks
    #pragma unroll
    for (int c = 0; c < 2; ++c) {
      int lin = tid + c * 256;            // 0..511
      int r = lin >> 2, k8 = (lin & 3) * 8;
      uint4 av = *(const uint4*)&A[(size_t)(m0 + r) * K + k0 + k8];
      *(uint4*)&sA[r][k8] = av;
    }
    // stage B: 128x32 fp32 -> bf16
    #pragma unroll
    for (int c = 0; c < 4; ++c) {
      int lin = tid + c * 256;            // 0..1023
      int r = lin >> 3, k4 = (lin & 7) * 4;
      int nrow = n0 + r;
      float4 bv = make_float4(0.f, 0.f, 0.f, 0.f);
      if (nrow < N) bv = *(const float4*)&B[(size_t)nrow * K + k0 + k4];
      ushort4 b4;
      b4.x = f2bf(bv.x); b4.y = f2bf(bv.y); b4.z = f2bf(bv.z); b4.w = f2bf(bv.w);
      *(ushort4*)&sB[r][k4] = b4;
    }
    __syncthreads();
    short8 af[4], bfm[4];
    #pragma unroll
    for (int mi = 0; mi < 4; ++mi) af[mi] = *(const short8*)&sA[wm + mi * 16 + fr][fc];
    #pragma unroll
    for (int ni = 0; ni < 4; ++ni) bfm[ni] = *(const short8*)&sB[wn + ni * 16 + fr][fc];
    #pragma unroll
    for (int mi = 0; mi < 4; ++mi)
      #pragma unroll
      for (int ni = 0; ni < 4; ++ni)
        acc[mi][ni] = __builtin_amdgcn_mfma_f32_16x16x32_bf16(af[mi], bfm[ni], acc[mi][ni], 0, 0, 0);
    __syncthreads();
  }

  const int fq = lane >> 4;
  #pragma unroll
  for (int mi = 0; mi < 4; ++mi)
    #pragma unroll
    for (int ni = 0; ni < 4; ++ni)
      #pragma unroll
      for (int r = 0; r < 4; ++r) {
        int row = m0 + wm + mi * 16 + fq * 4 + r;
        int col = n0 + wn + ni * 16 + fr;
        if (col < N) {
          float v = acc[mi][ni][r] + bias[col];
          if (RESID) v += resid[(size_t)row * N + col];
          C[(size_t)row * N + col] = v;
        }
      }
}

// ---------------- RoPE apply, in-place on qkv ----------------
__global__ __launch_bounds__(256) void rope_apply_kernel(
    float* __restrict__ qkv, const float* __restrict__ ctab, const float* __restrict__ stab) {
  int idx = blockIdx.x * 256 + threadIdx.x;       // (row, head(72), d(32))
  if (idx >= NTOK * 72 * 32) return;
  int d = idx & 31;
  int head = (idx >> 5) % 72;
  int row = idx / (72 * 32);
  int off = head < 64 ? head * 64 : KOFF + (head - 64) * 64;
  float* p = qkv + (size_t)row * QKVD + off;
  float c = ctab[row * 32 + d], s = stab[row * 32 + d];
  float x1 = p[d], x2 = p[d + 32];
  p[d]      = x1 * c - x2 * s;
  p[d + 32] = x2 * c + x1 * s;
}

// ---------------- Sliding-window attention with sinks ----------------
// grid: (32 q-tiles, 64 heads); block 256. Window=128 -> 192-key tile.
__global__ __launch_bounds__(256) void attn_kernel(
    const float* __restrict__ qkv, const float* __restrict__ sinks,
    unsigned short* __restrict__ attn) {
  const int tile = blockIdx.x;
  const int gh = blockIdx.y;
  const int h = gh >> 3;
  const int q0 = tile * 64;
  const int kbase = q0 - 127;

  __shared__ unsigned short Ksh[192][68];
  __shared__ unsigned short Vsh[192][68];
  __shared__ unsigned short Wsh[64][200];

  // stage K,V (bf16), zero-fill j<0
  for (int idx = threadIdx.x; idx < 192 * 16; idx += 256) {
    int r = idx >> 4, c4 = (idx & 15) * 4;
    int j = kbase + r;
    float4 kv = make_float4(0.f, 0.f, 0.f, 0.f);
    float4 vv = make_float4(0.f, 0.f, 0.f, 0.f);
    if (j >= 0) {
      kv = *(const float4*)&qkv[(size_t)j * QKVD + KOFF + h * 64 + c4];
      vv = *(const float4*)&qkv[(size_t)j * QKVD + VOFF + h * 64 + c4];
    }
    Ksh[r][c4 + 0] = f2bf(kv.x); Ksh[r][c4 + 1] = f2bf(kv.y);
    Ksh[r][c4 + 2] = f2bf(kv.z); Ksh[r][c4 + 3] = f2bf(kv.w);
    Vsh[r][c4 + 0] = f2bf(vv.x); Vsh[r][c4 + 1] = f2bf(vv.y);
    Vsh[r][c4 + 2] = f2bf(vv.z); Vsh[r][c4 + 3] = f2bf(vv.w);
  }
  __syncthreads();

  const int i_loc = threadIdx.x >> 2;
  const int p = threadIdx.x & 3;
  const int i = q0 + i_loc;

  // q row in registers
  float qr[64];
  #pragma unroll
  for (int c4 = 0; c4 < 16; ++c4) {
    float4 qv = *(const float4*)&qkv[(size_t)i * QKVD + gh * 64 + c4 * 4];
    qr[c4 * 4 + 0] = qv.x; qr[c4 * 4 + 1] = qv.y;
    qr[c4 * 4 + 2] = qv.z; qr[c4 * 4 + 3] = qv.w;
  }

  // scores: thread p handles keys kk = p + 4*s (bank-friendly); softmax w/o max-sub
  float sum = 0.f;
  #pragma unroll 2
  for (int s = 0; s < 48; ++s) {
    int kk = p + 4 * s;
    int j = kbase + kk;
    float d0 = 0.f, d1 = 0.f, d2 = 0.f, d3 = 0.f;
    #pragma unroll
    for (int c = 0; c < 16; ++c) {
      ushort4 k4 = *(const ushort4*)&Ksh[kk][c * 4];
      d0 = fmaf(qr[c * 4 + 0], bf2f(k4.x), d0);
      d1 = fmaf(qr[c * 4 + 1], bf2f(k4.y), d1);
      d2 = fmaf(qr[c * 4 + 2], bf2f(k4.z), d2);
      d3 = fmaf(qr[c * 4 + 3], bf2f(k4.w), d3);
    }
    float dot = (d0 + d1) + (d2 + d3);
    bool valid = (j >= 0) && (j <= i) && (j > i - 128);
    float pw = valid ? __expf(dot * 0.125f) : 0.f;
    sum += pw;
    Wsh[i_loc][kk] = f2bf(pw);
  }
  sum += __shfl_xor(sum, 1);
  sum += __shfl_xor(sum, 2);
  float sink = sinks[gh];
  float inv = 1.f / (sum + __expf(sink));
  __syncthreads();

  // PV: thread owns d-range [p*16, p*16+16), all 192 keys
  float acc[16] = {0.f, 0.f, 0.f, 0.f, 0.f, 0.f, 0.f, 0.f,
                   0.f, 0.f, 0.f, 0.f, 0.f, 0.f, 0.f, 0.f};
  #pragma unroll 2
  for (int kk = 0; kk < 192; ++kk) {
    float w = bf2f(Wsh[i_loc][kk]);
    #pragma unroll
    for (int c = 0; c < 4; ++c) {
      ushort4 v4 = *(const ushort4*)&Vsh[kk][p * 16 + c * 4];
      acc[c * 4 + 0] = fmaf(w, bf2f(v4.x), acc[c * 4 + 0]);
      acc[c * 4 + 1] = fmaf(w, bf2f(v4.y), acc[c * 4 + 1]);
      acc[c * 4 + 2] = fmaf(w, bf2f(v4.z), acc[c * 4 + 2]);
      acc[c * 4 + 3] = fmaf(w, bf2f(v4.w), acc[c * 4 + 3]);
    }
  }
  uint4 o0, o1;
  o0.x = pack2(acc[0] * inv,  acc[1] * inv);  o0.y = pack2(acc[2] * inv,  acc[3] * inv);
  o0.z = pack2(acc[4] * inv,  acc[5] * inv);  o0.w = pack2(acc[6] * inv,  acc[7] * inv);
  o1.x = pack2(acc[8] * inv,  acc[9] * inv);  o1.y = pack2(acc[10] * inv, acc[11] * inv);
  o1.z = pack2(acc[12] * inv, acc[13] * inv); o1.w = pack2(acc[14] * inv, acc[15] * inv);
  unsigned short* dst = &attn[(size_t)i * ATTD + gh * 64 + p * 16];
  *(uint4*)dst = o0;
  *(uint4*)(dst + 8) = o1;
}

extern "C" void kernel_launch(void* const* d_in, const int* in_sizes, int n_in,
                              void* d_out, int out_size, void* d_ws, size_t ws_size,
                              hipStream_t stream) {
  const float* x          = (const float*)d_in[0];
  const float* norm_scale = (const float*)d_in[1];
  const float* sinks      = (const float*)d_in[2];
  const float* w_qkv      = (const float*)d_in[3];
  const float* b_qkv      = (const float*)d_in[4];
  const float* w_out      = (const float*)d_in[5];
  const float* b_out      = (const float*)d_in[6];
  float* out = (float*)d_out;

  char* ws = (char*)d_ws;
  unsigned short* t_bf   = (unsigned short*)(ws);                 // 2048*2880*2  = 11,796,480
  float*          qkv    = (float*)(ws + 11796480);               // 2048*5120*4  = 41,943,040
  unsigned short* attn_b = (unsigned short*)(ws + 53739520);      // 2048*4096*2  = 16,777,216
  float*          ctab   = (float*)(ws + 70516736);               // 2048*32*4
  float*          stab   = (float*)(ws + 70778880);               // 2048*32*4 -> end 71,041,024

  rope_table_kernel<<<dim3(256), dim3(256), 0, stream>>>(ctab, stab);
  rmsnorm_kernel<<<dim3(NTOK), dim3(256), 0, stream>>>(x, norm_scale, t_bf);
  gemm_kernel<false><<<dim3(16, 40), dim3(256), 0, stream>>>(
      t_bf, w_qkv, b_qkv, nullptr, qkv, NTOK, QKVD, HID);
  rope_apply_kernel<<<dim3(18432), dim3(256), 0, stream>>>(qkv, ctab, stab);
  attn_kernel<<<dim3(32, 64), dim3(256), 0, stream>>>(qkv, sinks, attn_b);
  gemm_kernel<true><<<dim3(16, 23), dim3(256), 0, stream>>>(
      attn_b, w_out, b_out, x, out, NTOK, HID, ATTD);
}

// Round 2
// 424.333 us; speedup vs baseline: 1.5232x; 1.5232x over previous
//
#include <hip/hip_runtime.h>
#include <hip/hip_bf16.h>
#include <math.h>

typedef __attribute__((ext_vector_type(8))) short short8;
typedef __attribute__((ext_vector_type(4))) float f32x4;

#define NTOK 2048
#define HID  2880
#define QKVD 5120
#define KOFF 4096
#define VOFF 4608
#define ATTD 4096   // N_HEADS*HEAD_DIM

__device__ __forceinline__ unsigned short f2bf(float f) {
  union { float f; unsigned int u; } v; v.f = f;
  unsigned int u = v.u;
  unsigned int r = (u + 0x7FFFu + ((u >> 16) & 1u)) >> 16;
  return (unsigned short)r;
}
__device__ __forceinline__ float bf2f(unsigned short h) {
  union { unsigned int u; float f; } v; v.u = ((unsigned int)h) << 16; return v.f;
}
__device__ __forceinline__ unsigned int pack2(float a, float b) {
  return (unsigned int)f2bf(a) | ((unsigned int)f2bf(b) << 16);
}
__device__ __forceinline__ void gload_lds16(const unsigned short* g, unsigned short* l) {
  __builtin_amdgcn_global_load_lds(
      (const __attribute__((address_space(1))) unsigned int*)g,
      (__attribute__((address_space(3))) unsigned int*)l, 16, 0, 0);
}

// ---------------- RoPE cos/sin table (YaRN) ----------------
__global__ void rope_table_kernel(float* __restrict__ ctab, float* __restrict__ stab) {
  int idx = blockIdx.x * 256 + threadIdx.x;
  if (idx >= NTOK * 32) return;
  int pos = idx >> 5, i = idx & 31;
  const double theta = 150000.0;
  const double two_pi = 6.283185307179586476925286766559;
  double freq = pow(theta, (double)i / 32.0);
  double interp = 1.0 / (32.0 * freq);
  double extrap = 1.0 / freq;
  double low  = 32.0 * log(4096.0 / (32.0 * two_pi)) / log(theta);
  double high = 32.0 * log(4096.0 / (1.0  * two_pi)) / log(theta);
  double ramp = ((double)i - low) / (high - low);
  ramp = ramp < 0.0 ? 0.0 : (ramp > 1.0 ? 1.0 : ramp);
  double maskv = 1.0 - ramp;
  double inv = interp * (1.0 - maskv) + extrap * maskv;
  double ang = (double)pos * inv;
  double conc = 0.1 * log(32.0) + 1.0;
  ctab[idx] = (float)(cos(ang) * conc);
  stab[idx] = (float)(sin(ang) * conc);
}

// ---------------- RMSNorm fp32 -> bf16 (vectorized) ----------------
__global__ __launch_bounds__(256) void rmsnorm_kernel(
    const float* __restrict__ x, const float* __restrict__ scale,
    unsigned short* __restrict__ t) {
  int row = blockIdx.x;
  const float4* xr = (const float4*)(x + (size_t)row * HID);
  const float4* sc = (const float4*)scale;
  float ss = 0.f;
  for (int c = threadIdx.x; c < HID / 4; c += 256) {
    float4 v = xr[c];
    ss += v.x * v.x + v.y * v.y + v.z * v.z + v.w * v.w;
  }
  #pragma unroll
  for (int m = 1; m < 64; m <<= 1) ss += __shfl_xor(ss, m);
  __shared__ float red[4];
  if ((threadIdx.x & 63) == 0) red[threadIdx.x >> 6] = ss;
  __syncthreads();
  float tot = red[0] + red[1] + red[2] + red[3];
  float rs = rsqrtf(tot / (float)HID + 1e-5f);
  for (int c = threadIdx.x; c < HID / 4; c += 256) {
    float4 v = xr[c];
    float4 s4 = sc[c];
    ushort4 o;
    o.x = f2bf(v.x * rs * s4.x); o.y = f2bf(v.y * rs * s4.y);
    o.z = f2bf(v.z * rs * s4.z); o.w = f2bf(v.w * rs * s4.w);
    *(ushort4*)&t[(size_t)row * HID + c * 4] = o;
  }
}

// ---------------- Weight fp32 -> bf16 (with row padding) ----------------
__global__ __launch_bounds__(256) void cvt_w_kernel(
    const float* __restrict__ w, unsigned short* __restrict__ wb,
    int K, int rows_real, long total4) {
  long idx = (long)blockIdx.x * 256 + threadIdx.x;
  if (idx >= total4) return;
  long base = idx * 4;
  int row = (int)(base / K);
  ushort4 o;
  if (row < rows_real) {
    float4 v = *(const float4*)&w[base];
    o.x = f2bf(v.x); o.y = f2bf(v.y); o.z = f2bf(v.z); o.w = f2bf(v.w);
  } else {
    o.x = 0; o.y = 0; o.z = 0; o.w = 0;
  }
  *(ushort4*)&wb[base] = o;
}

// ---------------- GEMM (m97 structure): C[M,Nreal] = A[M,K]bf16 @ B[Npad,K]bf16^T + bias (+resid) ----
template<bool RESID>
__global__ __launch_bounds__(256) void gemm_bf16_kernel(
    const unsigned short* __restrict__ A, const unsigned short* __restrict__ B,
    const float* __restrict__ bias, const float* __restrict__ resid,
    float* __restrict__ C, int K, int Nreal) {
  __shared__ unsigned short sA[128 * 32];
  __shared__ unsigned short sB[128 * 32];
  const int m0 = blockIdx.x * 128;
  const int n0 = blockIdx.y * 128;
  const int tid = threadIdx.x;
  const int lane = tid & 63;
  const int wid = tid >> 6;
  const int wm = (wid >> 1) * 64;
  const int wn = (wid & 1) * 64;
  const int fr = lane & 15;
  const int fc = (lane >> 4) * 8;

  f32x4 acc[4][4] = {};

  const unsigned short* Ab = A + (size_t)m0 * K;
  const unsigned short* Bb = B + (size_t)n0 * K;

  // staging geometry: lin = c*256 + tid; row = lin>>2, 16B chunk = (lin&3)
  const int r0 = tid >> 2,          ch0 = (tid & 3) * 8;
  const int r1 = (tid + 256) >> 2,  ch1 = (tid & 3) * 8;
  unsigned short* ldsA0 = &sA[wid * 512];
  unsigned short* ldsA1 = &sA[2048 + wid * 512];
  unsigned short* ldsB0 = &sB[wid * 512];
  unsigned short* ldsB1 = &sB[2048 + wid * 512];

  for (int k0 = 0; k0 < K; k0 += 32) {
    gload_lds16(Ab + (size_t)r0 * K + k0 + ch0, ldsA0);
    gload_lds16(Ab + (size_t)r1 * K + k0 + ch1, ldsA1);
    gload_lds16(Bb + (size_t)r0 * K + k0 + ch0, ldsB0);
    gload_lds16(Bb + (size_t)r1 * K + k0 + ch1, ldsB1);
    __syncthreads();
    short8 af[4], bfm[4];
    #pragma unroll
    for (int mi = 0; mi < 4; ++mi) af[mi] = *(const short8*)&sA[(wm + mi * 16 + fr) * 32 + fc];
    #pragma unroll
    for (int ni = 0; ni < 4; ++ni) bfm[ni] = *(const short8*)&sB[(wn + ni * 16 + fr) * 32 + fc];
    #pragma unroll
    for (int mi = 0; mi < 4; ++mi)
      #pragma unroll
      for (int ni = 0; ni < 4; ++ni)
        acc[mi][ni] = __builtin_amdgcn_mfma_f32_16x16x32_bf16(af[mi], bfm[ni], acc[mi][ni], 0, 0, 0);
    __syncthreads();
  }

  const int fq = lane >> 4;
  #pragma unroll
  for (int mi = 0; mi < 4; ++mi)
    #pragma unroll
    for (int ni = 0; ni < 4; ++ni)
      #pragma unroll
      for (int r = 0; r < 4; ++r) {
        int row = m0 + wm + mi * 16 + fq * 4 + r;
        int col = n0 + wn + ni * 16 + fr;
        if (col < Nreal) {
          float v = acc[mi][ni][r] + bias[col];
          if (RESID) v += resid[(size_t)row * Nreal + col];
          C[(size_t)row * Nreal + col] = v;
        }
      }
}

// ---------------- RoPE apply, in-place on qkv ----------------
__global__ __launch_bounds__(256) void rope_apply_kernel(
    float* __restrict__ qkv, const float* __restrict__ ctab, const float* __restrict__ stab) {
  int idx = blockIdx.x * 256 + threadIdx.x;       // (row, head(72), d(32))
  if (idx >= NTOK * 72 * 32) return;
  int d = idx & 31;
  int head = (idx >> 5) % 72;
  int row = idx / (72 * 32);
  int off = head < 64 ? head * 64 : KOFF + (head - 64) * 64;
  float* p = qkv + (size_t)row * QKVD + off;
  float c = ctab[row * 32 + d], s = stab[row * 32 + d];
  float x1 = p[d], x2 = p[d + 32];
  p[d]      = x1 * c - x2 * s;
  p[d + 32] = x2 * c + x1 * s;
}

// ---------------- Sliding-window attention with sinks ----------------
__global__ __launch_bounds__(256) void attn_kernel(
    const float* __restrict__ qkv, const float* __restrict__ sinks,
    unsigned short* __restrict__ attn) {
  const int tile = blockIdx.x;
  const int gh = blockIdx.y;
  const int h = gh >> 3;
  const int q0 = tile * 64;
  const int kbase = q0 - 127;

  __shared__ unsigned short Ksh[192][68];
  __shared__ unsigned short Vsh[192][68];
  __shared__ unsigned short Wsh[64][200];

  for (int idx = threadIdx.x; idx < 192 * 16; idx += 256) {
    int r = idx >> 4, c4 = (idx & 15) * 4;
    int j = kbase + r;
    float4 kv = make_float4(0.f, 0.f, 0.f, 0.f);
    float4 vv = make_float4(0.f, 0.f, 0.f, 0.f);
    if (j >= 0) {
      kv = *(const float4*)&qkv[(size_t)j * QKVD + KOFF + h * 64 + c4];
      vv = *(const float4*)&qkv[(size_t)j * QKVD + VOFF + h * 64 + c4];
    }
    Ksh[r][c4 + 0] = f2bf(kv.x); Ksh[r][c4 + 1] = f2bf(kv.y);
    Ksh[r][c4 + 2] = f2bf(kv.z); Ksh[r][c4 + 3] = f2bf(kv.w);
    Vsh[r][c4 + 0] = f2bf(vv.x); Vsh[r][c4 + 1] = f2bf(vv.y);
    Vsh[r][c4 + 2] = f2bf(vv.z); Vsh[r][c4 + 3] = f2bf(vv.w);
  }
  __syncthreads();

  const int i_loc = threadIdx.x >> 2;
  const int p = threadIdx.x & 3;
  const int i = q0 + i_loc;

  float qr[64];
  #pragma unroll
  for (int c4 = 0; c4 < 16; ++c4) {
    float4 qv = *(const float4*)&qkv[(size_t)i * QKVD + gh * 64 + c4 * 4];
    qr[c4 * 4 + 0] = qv.x; qr[c4 * 4 + 1] = qv.y;
    qr[c4 * 4 + 2] = qv.z; qr[c4 * 4 + 3] = qv.w;
  }

  float sum = 0.f;
  #pragma unroll 2
  for (int s = 0; s < 48; ++s) {
    int kk = p + 4 * s;
    int j = kbase + kk;
    float d0 = 0.f, d1 = 0.f, d2 = 0.f, d3 = 0.f;
    #pragma unroll
    for (int c = 0; c < 16; ++c) {
      ushort4 k4 = *(const ushort4*)&Ksh[kk][c * 4];
      d0 = fmaf(qr[c * 4 + 0], bf2f(k4.x), d0);
      d1 = fmaf(qr[c * 4 + 1], bf2f(k4.y), d1);
      d2 = fmaf(qr[c * 4 + 2], bf2f(k4.z), d2);
      d3 = fmaf(qr[c * 4 + 3], bf2f(k4.w), d3);
    }
    float dot = (d0 + d1) + (d2 + d3);
    bool valid = (j >= 0) && (j <= i) && (j > i - 128);
    float pw = valid ? __expf(dot * 0.125f) : 0.f;
    sum += pw;
    Wsh[i_loc][kk] = f2bf(pw);
  }
  sum += __shfl_xor(sum, 1);
  sum += __shfl_xor(sum, 2);
  float sink = sinks[gh];
  float inv = 1.f / (sum + __expf(sink));
  __syncthreads();

  float acc[16] = {0.f, 0.f, 0.f, 0.f, 0.f, 0.f, 0.f, 0.f,
                   0.f, 0.f, 0.f, 0.f, 0.f, 0.f, 0.f, 0.f};
  #pragma unroll 2
  for (int kk = 0; kk < 192; ++kk) {
    float w = bf2f(Wsh[i_loc][kk]);
    #pragma unroll
    for (int c = 0; c < 4; ++c) {
      ushort4 v4 = *(const ushort4*)&Vsh[kk][p * 16 + c * 4];
      acc[c * 4 + 0] = fmaf(w, bf2f(v4.x), acc[c * 4 + 0]);
      acc[c * 4 + 1] = fmaf(w, bf2f(v4.y), acc[c * 4 + 1]);
      acc[c * 4 + 2] = fmaf(w, bf2f(v4.z), acc[c * 4 + 2]);
      acc[c * 4 + 3] = fmaf(w, bf2f(v4.w), acc[c * 4 + 3]);
    }
  }
  uint4 o0, o1;
  o0.x = pack2(acc[0] * inv,  acc[1] * inv);  o0.y = pack2(acc[2] * inv,  acc[3] * inv);
  o0.z = pack2(acc[4] * inv,  acc[5] * inv);  o0.w = pack2(acc[6] * inv,  acc[7] * inv);
  o1.x = pack2(acc[8] * inv,  acc[9] * inv);  o1.y = pack2(acc[10] * inv, acc[11] * inv);
  o1.z = pack2(acc[12] * inv, acc[13] * inv); o1.w = pack2(acc[14] * inv, acc[15] * inv);
  unsigned short* dst = &attn[(size_t)i * ATTD + gh * 64 + p * 16];
  *(uint4*)dst = o0;
  *(uint4*)(dst + 8) = o1;
}

extern "C" void kernel_launch(void* const* d_in, const int* in_sizes, int n_in,
                              void* d_out, int out_size, void* d_ws, size_t ws_size,
                              hipStream_t stream) {
  const float* x          = (const float*)d_in[0];
  const float* norm_scale = (const float*)d_in[1];
  const float* sinks      = (const float*)d_in[2];
  const float* w_qkv      = (const float*)d_in[3];
  const float* b_qkv      = (const float*)d_in[4];
  const float* w_out      = (const float*)d_in[5];
  const float* b_out      = (const float*)d_in[6];
  float* out = (float*)d_out;

  // workspace layout (overlapping dead regions):
  //   [0, 16.8MB)    : t_bf (11.8MB, dead after gemm1)  /  attn_b (16.8MB, written by attn)
  //   [16.8, 58.7MB) : qkv fp32 (41.9MB)
  //   [58.7, 88.2MB) : w_qkv_bf (29.5MB, dead after gemm1) / w_out_bf padded 2944x4096 (24.1MB)
  //   [88.2, 88.7MB) : ctab, stab
  char* ws = (char*)d_ws;
  unsigned short* t_bf   = (unsigned short*)(ws);
  unsigned short* attn_b = (unsigned short*)(ws);
  float*          qkv    = (float*)(ws + 16777216);
  unsigned short* wbf    = (unsigned short*)(ws + 16777216 + 41943040);
  float*          ctab   = (float*)(ws + 16777216 + 41943040 + 29491200);
  float*          stab   = ctab + NTOK * 32;

  rope_table_kernel<<<dim3(256), dim3(256), 0, stream>>>(ctab, stab);
  rmsnorm_kernel<<<dim3(NTOK), dim3(256), 0, stream>>>(x, norm_scale, t_bf);
  // w_qkv: 5120x2880 fp32 -> bf16 (no pad): total4 = 3,686,400
  cvt_w_kernel<<<dim3(14400), dim3(256), 0, stream>>>(w_qkv, wbf, HID, QKVD, 3686400L);
  gemm_bf16_kernel<false><<<dim3(16, 40), dim3(256), 0, stream>>>(
      t_bf, wbf, b_qkv, nullptr, qkv, HID, QKVD);
  rope_apply_kernel<<<dim3(18432), dim3(256), 0, stream>>>(qkv, ctab, stab);
  attn_kernel<<<dim3(32, 64), dim3(256), 0, stream>>>(qkv, sinks, attn_b);
  // w_out: 2880x4096 fp32 -> bf16 padded to 2944 rows: total4 = 2944*4096/4 = 3,014,656
  cvt_w_kernel<<<dim3(11776), dim3(256), 0, stream>>>(w_out, wbf, ATTD, HID, 3014656L);
  gemm_bf16_kernel<true><<<dim3(16, 23), dim3(256), 0, stream>>>(
      attn_b, wbf, b_out, x, out, ATTD, HID);
}

// Round 3
// 278.705 us; speedup vs baseline: 2.3190x; 1.5225x over previous
//
#include <hip/hip_runtime.h>
#include <hip/hip_bf16.h>
#include <math.h>

typedef __attribute__((ext_vector_type(8))) short short8;
typedef __attribute__((ext_vector_type(4))) float f32x4;

#define NTOK 2048
#define HID  2880
#define QKVD 5120
#define KOFF 4096
#define VOFF 4608
#define ATTD 4096   // N_HEADS*HEAD_DIM

__device__ __forceinline__ unsigned short f2bf(float f) {
  union { float f; unsigned int u; } v; v.f = f;
  unsigned int u = v.u;
  unsigned int r = (u + 0x7FFFu + ((u >> 16) & 1u)) >> 16;
  return (unsigned short)r;
}
__device__ __forceinline__ float bf2f(unsigned short h) {
  union { unsigned int u; float f; } v; v.u = ((unsigned int)h) << 16; return v.f;
}
__device__ __forceinline__ void gload_lds16(const unsigned short* g, unsigned short* l) {
  __builtin_amdgcn_global_load_lds(
      (const __attribute__((address_space(1))) unsigned int*)g,
      (__attribute__((address_space(3))) unsigned int*)l, 16, 0, 0);
}

// ---------------- RoPE cos/sin table (YaRN) ----------------
__global__ void rope_table_kernel(float* __restrict__ ctab, float* __restrict__ stab) {
  int idx = blockIdx.x * 256 + threadIdx.x;
  if (idx >= NTOK * 32) return;
  int pos = idx >> 5, i = idx & 31;
  const double theta = 150000.0;
  const double two_pi = 6.283185307179586476925286766559;
  double freq = pow(theta, (double)i / 32.0);
  double interp = 1.0 / (32.0 * freq);
  double extrap = 1.0 / freq;
  double low  = 32.0 * log(4096.0 / (32.0 * two_pi)) / log(theta);
  double high = 32.0 * log(4096.0 / (1.0  * two_pi)) / log(theta);
  double ramp = ((double)i - low) / (high - low);
  ramp = ramp < 0.0 ? 0.0 : (ramp > 1.0 ? 1.0 : ramp);
  double maskv = 1.0 - ramp;
  double inv = interp * (1.0 - maskv) + extrap * maskv;
  double ang = (double)pos * inv;
  double conc = 0.1 * log(32.0) + 1.0;
  ctab[idx] = (float)(cos(ang) * conc);
  stab[idx] = (float)(sin(ang) * conc);
}

// ---------------- RMSNorm fp32 -> bf16 (vectorized) ----------------
__global__ __launch_bounds__(256) void rmsnorm_kernel(
    const float* __restrict__ x, const float* __restrict__ scale,
    unsigned short* __restrict__ t) {
  int row = blockIdx.x;
  const float4* xr = (const float4*)(x + (size_t)row * HID);
  const float4* sc = (const float4*)scale;
  float ss = 0.f;
  for (int c = threadIdx.x; c < HID / 4; c += 256) {
    float4 v = xr[c];
    ss += v.x * v.x + v.y * v.y + v.z * v.z + v.w * v.w;
  }
  #pragma unroll
  for (int m = 1; m < 64; m <<= 1) ss += __shfl_xor(ss, m);
  __shared__ float red[4];
  if ((threadIdx.x & 63) == 0) red[threadIdx.x >> 6] = ss;
  __syncthreads();
  float tot = red[0] + red[1] + red[2] + red[3];
  float rs = rsqrtf(tot / (float)HID + 1e-5f);
  for (int c = threadIdx.x; c < HID / 4; c += 256) {
    float4 v = xr[c];
    float4 s4 = sc[c];
    ushort4 o;
    o.x = f2bf(v.x * rs * s4.x); o.y = f2bf(v.y * rs * s4.y);
    o.z = f2bf(v.z * rs * s4.z); o.w = f2bf(v.w * rs * s4.w);
    *(ushort4*)&t[(size_t)row * HID + c * 4] = o;
  }
}

// ---------------- Weight fp32 -> bf16 (with row padding) ----------------
__global__ __launch_bounds__(256) void cvt_w_kernel(
    const float* __restrict__ w, unsigned short* __restrict__ wb,
    int K, int rows_real, long total4) {
  long idx = (long)blockIdx.x * 256 + threadIdx.x;
  if (idx >= total4) return;
  long base = idx * 4;
  int row = (int)(base / K);
  ushort4 o;
  if (row < rows_real) {
    float4 v = *(const float4*)&w[base];
    o.x = f2bf(v.x); o.y = f2bf(v.y); o.z = f2bf(v.z); o.w = f2bf(v.w);
  } else {
    o.x = 0; o.y = 0; o.z = 0; o.w = 0;
  }
  *(ushort4*)&wb[base] = o;
}

// ---------------- GEMM (m97 structure) ----------------
// MODE 0: C bf16 = A@B^T + bias, RoPE fused on heads 0..71 (GEMM1, N=5120 exact)
// MODE 1: C f32  = A@B^T + bias + resid, col<Nreal guard (GEMM2)
template<int MODE>
__global__ __launch_bounds__(256) void gemm_bf16_kernel(
    const unsigned short* __restrict__ A, const unsigned short* __restrict__ B,
    const float* __restrict__ bias, const float* __restrict__ resid,
    void* __restrict__ Cout, int K, int Nreal,
    const float* __restrict__ ctab, const float* __restrict__ stab) {
  __shared__ unsigned short sA[128 * 32];
  __shared__ unsigned short sB[128 * 32];
  const int m0 = blockIdx.x * 128;
  const int n0 = blockIdx.y * 128;
  const int tid = threadIdx.x;
  const int lane = tid & 63;
  const int wid = tid >> 6;
  const int wm = (wid >> 1) * 64;
  const int wn = (wid & 1) * 64;
  const int fr = lane & 15;
  const int fc = (lane >> 4) * 8;

  f32x4 acc[4][4] = {};

  const unsigned short* Ab = A + (size_t)m0 * K;
  const unsigned short* Bb = B + (size_t)n0 * K;

  const int r0 = tid >> 2,          ch0 = (tid & 3) * 8;
  const int r1 = (tid + 256) >> 2,  ch1 = (tid & 3) * 8;
  unsigned short* ldsA0 = &sA[wid * 512];
  unsigned short* ldsA1 = &sA[2048 + wid * 512];
  unsigned short* ldsB0 = &sB[wid * 512];
  unsigned short* ldsB1 = &sB[2048 + wid * 512];

  for (int k0 = 0; k0 < K; k0 += 32) {
    gload_lds16(Ab + (size_t)r0 * K + k0 + ch0, ldsA0);
    gload_lds16(Ab + (size_t)r1 * K + k0 + ch1, ldsA1);
    gload_lds16(Bb + (size_t)r0 * K + k0 + ch0, ldsB0);
    gload_lds16(Bb + (size_t)r1 * K + k0 + ch1, ldsB1);
    __syncthreads();
    short8 af[4], bfm[4];
    #pragma unroll
    for (int mi = 0; mi < 4; ++mi) af[mi] = *(const short8*)&sA[(wm + mi * 16 + fr) * 32 + fc];
    #pragma unroll
    for (int ni = 0; ni < 4; ++ni) bfm[ni] = *(const short8*)&sB[(wn + ni * 16 + fr) * 32 + fc];
    #pragma unroll
    for (int mi = 0; mi < 4; ++mi)
      #pragma unroll
      for (int ni = 0; ni < 4; ++ni)
        acc[mi][ni] = __builtin_amdgcn_mfma_f32_16x16x32_bf16(af[mi], bfm[ni], acc[mi][ni], 0, 0, 0);
    __syncthreads();
  }

  const int fq = lane >> 4;
  if (MODE == 0) {
    unsigned short* C = (unsigned short*)Cout;
    const int head = (n0 + wn) >> 6;   // wave-uniform: one head per 64-col wave block
    #pragma unroll
    for (int mi = 0; mi < 4; ++mi)
      #pragma unroll
      for (int r = 0; r < 4; ++r) {
        int row = m0 + wm + mi * 16 + fq * 4 + r;
        size_t rowoff = (size_t)row * Nreal;
        if (head < 72) {
          #pragma unroll
          for (int ni = 0; ni < 2; ++ni) {
            int col1 = n0 + wn + ni * 16 + fr;
            int d = ni * 16 + fr;
            float c = ctab[row * 32 + d], s = stab[row * 32 + d];
            float x1 = acc[mi][ni][r] + bias[col1];
            float x2 = acc[mi][ni + 2][r] + bias[col1 + 32];
            C[rowoff + col1]      = f2bf(x1 * c - x2 * s);
            C[rowoff + col1 + 32] = f2bf(x2 * c + x1 * s);
          }
        } else {
          #pragma unroll
          for (int ni = 0; ni < 4; ++ni) {
            int col = n0 + wn + ni * 16 + fr;
            C[rowoff + col] = f2bf(acc[mi][ni][r] + bias[col]);
          }
        }
      }
  } else {
    float* C = (float*)Cout;
    #pragma unroll
    for (int mi = 0; mi < 4; ++mi)
      #pragma unroll
      for (int ni = 0; ni < 4; ++ni)
        #pragma unroll
        for (int r = 0; r < 4; ++r) {
          int row = m0 + wm + mi * 16 + fq * 4 + r;
          int col = n0 + wn + ni * 16 + fr;
          if (col < Nreal) {
            float v = acc[mi][ni][r] + bias[col] + resid[(size_t)row * Nreal + col];
            C[(size_t)row * Nreal + col] = v;
          }
        }
  }
}

// ---------------- MFMA sliding-window attention with sinks ----------------
// grid (32 q-tiles, 64 q-heads), block 256 (4 waves).
// Per block: Q 64x64, keys j in [q0-127, q0+64] (192), scores via MFMA,
// in-register exp+mask, P->LDS bf16 (overlay K buffer), PV via MFMA.
__global__ __launch_bounds__(256) void attn_kernel(
    const unsigned short* __restrict__ qkv, const float* __restrict__ sinks,
    unsigned short* __restrict__ attn) {
  const int tile = blockIdx.x;
  const int gh = blockIdx.y;
  const int h = gh >> 3;
  const int q0 = tile * 64;
  const int kbase = q0 - 127;

  __shared__ unsigned short Qsh[64][72];
  __shared__ unsigned short Ksh[192][72];
  __shared__ unsigned short Vt[64][200];    // transposed V: [dim][key]
  __shared__ float rowpart[4][64];
  __shared__ float invsum[64];
  unsigned short (*Wsh)[200] = (unsigned short (*)[200])Ksh;  // overlay after scores

  const int tid = threadIdx.x;
  // ---- stage Q (64x64): 512 chunks of 8 bf16
  #pragma unroll
  for (int c = 0; c < 2; ++c) {
    int lin = tid + c * 256;
    int r = lin >> 3, ch = (lin & 7) * 8;
    uint4 v = *(const uint4*)&qkv[(size_t)(q0 + r) * QKVD + gh * 64 + ch];
    *(uint4*)&Qsh[r][ch] = v;
  }
  // ---- stage K (192x64) with bounds zero-fill
  #pragma unroll
  for (int c = 0; c < 6; ++c) {
    int lin = tid + c * 256;
    int r = lin >> 3, ch = (lin & 7) * 8;
    int j = kbase + r;
    uint4 v = make_uint4(0u, 0u, 0u, 0u);
    if (j >= 0 && j < NTOK) v = *(const uint4*)&qkv[(size_t)j * QKVD + KOFF + h * 64 + ch];
    *(uint4*)&Ksh[r][ch] = v;
  }
  // ---- stage V transposed: Vt[dim][key]
  #pragma unroll
  for (int c = 0; c < 6; ++c) {
    int lin = tid + c * 256;
    int r = lin >> 3, ch = (lin & 7) * 8;
    int j = kbase + r;
    uint4 v = make_uint4(0u, 0u, 0u, 0u);
    if (j >= 0 && j < NTOK) v = *(const uint4*)&qkv[(size_t)j * QKVD + VOFF + h * 64 + ch];
    const unsigned short* vs = (const unsigned short*)&v;
    #pragma unroll
    for (int i2 = 0; i2 < 8; ++i2) Vt[ch + i2][r] = vs[i2];
  }
  __syncthreads();

  const int lane = tid & 63;
  const int wid = tid >> 6;
  const int fr = lane & 15;
  const int fq = lane >> 4;
  const int fc = fq * 8;
  const int wk0 = wid * 48;     // this wave's 48-key range

  // ---- scores: S[64][48] per wave
  f32x4 sc[4][3] = {};
  #pragma unroll
  for (int k0 = 0; k0 < 64; k0 += 32) {
    short8 qa[4], kb[3];
    #pragma unroll
    for (int mi = 0; mi < 4; ++mi) qa[mi] = *(const short8*)&Qsh[mi * 16 + fr][k0 + fc];
    #pragma unroll
    for (int ni = 0; ni < 3; ++ni) kb[ni] = *(const short8*)&Ksh[wk0 + ni * 16 + fr][k0 + fc];
    #pragma unroll
    for (int mi = 0; mi < 4; ++mi)
      #pragma unroll
      for (int ni = 0; ni < 3; ++ni)
        sc[mi][ni] = __builtin_amdgcn_mfma_f32_16x16x32_bf16(qa[mi], kb[ni], sc[mi][ni], 0, 0, 0);
  }

  // ---- mask + exp in-register; per-row partial sums (this wave's 48 keys)
  float rsum[4][4];
  #pragma unroll
  for (int mi = 0; mi < 4; ++mi)
    #pragma unroll
    for (int r = 0; r < 4; ++r) {
      int i = q0 + mi * 16 + fq * 4 + r;
      float rs = 0.f;
      #pragma unroll
      for (int ni = 0; ni < 3; ++ni) {
        int kk = wk0 + ni * 16 + fr;
        int j = kbase + kk;
        bool valid = (j >= 0) && (j <= i) && (j > i - 128);
        float pw = valid ? __expf(sc[mi][ni][r] * 0.125f) : 0.f;
        sc[mi][ni][r] = pw;
        rs += pw;
      }
      // reduce across the 16 lanes sharing fq
      rs += __shfl_xor(rs, 1);
      rs += __shfl_xor(rs, 2);
      rs += __shfl_xor(rs, 4);
      rs += __shfl_xor(rs, 8);
      rsum[mi][r] = rs;
    }

  __syncthreads();   // all Ksh reads complete; safe to overlay Wsh

  // ---- write P (bf16) and row partials
  #pragma unroll
  for (int mi = 0; mi < 4; ++mi)
    #pragma unroll
    for (int r = 0; r < 4; ++r) {
      int row = mi * 16 + fq * 4 + r;
      #pragma unroll
      for (int ni = 0; ni < 3; ++ni)
        Wsh[row][wk0 + ni * 16 + fr] = f2bf(sc[mi][ni][r]);
      if (fr == 0) rowpart[wid][row] = rsum[mi][r];
    }
  __syncthreads();

  if (tid < 64) {
    float tot = rowpart[0][tid] + rowpart[1][tid] + rowpart[2][tid] + rowpart[3][tid];
    invsum[tid] = 1.f / (tot + __expf(sinks[gh]));
  }

  // ---- PV: out[64][16] per wave (cols wid*16..+16), K=192
  f32x4 pv[4] = {};
  #pragma unroll
  for (int k0 = 0; k0 < 192; k0 += 32) {
    short8 pa[4];
    #pragma unroll
    for (int mi = 0; mi < 4; ++mi) pa[mi] = *(const short8*)&Wsh[mi * 16 + fr][k0 + fc];
    short8 vb = *(const short8*)&Vt[wid * 16 + fr][k0 + fc];
    #pragma unroll
    for (int mi = 0; mi < 4; ++mi)
      pv[mi] = __builtin_amdgcn_mfma_f32_16x16x32_bf16(pa[mi], vb, pv[mi], 0, 0, 0);
  }
  __syncthreads();   // invsum visible

  #pragma unroll
  for (int mi = 0; mi < 4; ++mi)
    #pragma unroll
    for (int r = 0; r < 4; ++r) {
      int row = mi * 16 + fq * 4 + r;
      float inv = invsum[row];
      int col = wid * 16 + fr;
      attn[(size_t)(q0 + row) * ATTD + gh * 64 + col] = f2bf(pv[mi][r] * inv);
    }
}

extern "C" void kernel_launch(void* const* d_in, const int* in_sizes, int n_in,
                              void* d_out, int out_size, void* d_ws, size_t ws_size,
                              hipStream_t stream) {
  const float* x          = (const float*)d_in[0];
  const float* norm_scale = (const float*)d_in[1];
  const float* sinks      = (const float*)d_in[2];
  const float* w_qkv      = (const float*)d_in[3];
  const float* b_qkv      = (const float*)d_in[4];
  const float* w_out      = (const float*)d_in[5];
  const float* b_out      = (const float*)d_in[6];
  float* out = (float*)d_out;

  // workspace:
  //   [0, 21.0MB)     qkv_bf  (2048x5120 bf16)
  //   [21.0, 37.7MB)  t_bf (11.8MB, dead after gemm1) overlaid by attn_b (16.8MB)
  //   [37.7, 67.2MB)  wbf (w_qkv_bf 29.5MB, then w_out_bf padded 24.1MB)
  //   [67.2, 67.8MB)  ctab, stab
  char* ws = (char*)d_ws;
  unsigned short* qkv_bf = (unsigned short*)(ws);
  unsigned short* t_bf   = (unsigned short*)(ws + 20971520);
  unsigned short* attn_b = (unsigned short*)(ws + 20971520);
  unsigned short* wbf    = (unsigned short*)(ws + 20971520 + 16777216);
  float*          ctab   = (float*)(ws + 20971520 + 16777216 + 29491200);
  float*          stab   = ctab + NTOK * 32;

  rope_table_kernel<<<dim3(256), dim3(256), 0, stream>>>(ctab, stab);
  rmsnorm_kernel<<<dim3(NTOK), dim3(256), 0, stream>>>(x, norm_scale, t_bf);
  cvt_w_kernel<<<dim3(14400), dim3(256), 0, stream>>>(w_qkv, wbf, HID, QKVD, 3686400L);
  gemm_bf16_kernel<0><<<dim3(16, 40), dim3(256), 0, stream>>>(
      t_bf, wbf, b_qkv, nullptr, (void*)qkv_bf, HID, QKVD, ctab, stab);
  attn_kernel<<<dim3(32, 64), dim3(256), 0, stream>>>(qkv_bf, sinks, attn_b);
  cvt_w_kernel<<<dim3(11776), dim3(256), 0, stream>>>(w_out, wbf, ATTD, HID, 3014656L);
  gemm_bf16_kernel<1><<<dim3(16, 23), dim3(256), 0, stream>>>(
      attn_b, wbf, b_out, x, (void*)out, ATTD, HID, ctab, stab);
}

// Round 4
// 249.745 us; speedup vs baseline: 2.5880x; 1.1160x over previous
//
#include <hip/hip_runtime.h>
#include <hip/hip_bf16.h>
#include <math.h>

typedef __attribute__((ext_vector_type(8))) short short8;
typedef __attribute__((ext_vector_type(4))) float f32x4;
typedef unsigned short ushort_t;

#define NTOK 2048
#define HID  2880
#define QKVD 5120
#define KOFF 4096
#define VOFF 4608
#define ATTD 4096   // N_HEADS*HEAD_DIM

__device__ __forceinline__ unsigned short f2bf(float f) {
  union { float f; unsigned int u; } v; v.f = f;
  unsigned int u = v.u;
  unsigned int r = (u + 0x7FFFu + ((u >> 16) & 1u)) >> 16;
  return (unsigned short)r;
}
__device__ __forceinline__ float bf2f(unsigned short h) {
  union { unsigned int u; float f; } v; v.u = ((unsigned int)h) << 16; return v.f;
}
__device__ __forceinline__ void gload_lds16(const unsigned short* g, unsigned short* l) {
  __builtin_amdgcn_global_load_lds(
      (const __attribute__((address_space(1))) unsigned int*)g,
      (__attribute__((address_space(3))) unsigned int*)l, 16, 0, 0);
}

// ---------------- RoPE cos/sin table (YaRN) ----------------
__global__ void rope_table_kernel(float* __restrict__ ctab, float* __restrict__ stab) {
  int idx = blockIdx.x * 256 + threadIdx.x;
  if (idx >= NTOK * 32) return;
  int pos = idx >> 5, i = idx & 31;
  const double theta = 150000.0;
  const double two_pi = 6.283185307179586476925286766559;
  double freq = pow(theta, (double)i / 32.0);
  double interp = 1.0 / (32.0 * freq);
  double extrap = 1.0 / freq;
  double low  = 32.0 * log(4096.0 / (32.0 * two_pi)) / log(theta);
  double high = 32.0 * log(4096.0 / (1.0  * two_pi)) / log(theta);
  double ramp = ((double)i - low) / (high - low);
  ramp = ramp < 0.0 ? 0.0 : (ramp > 1.0 ? 1.0 : ramp);
  double maskv = 1.0 - ramp;
  double inv = interp * (1.0 - maskv) + extrap * maskv;
  double ang = (double)pos * inv;
  double conc = 0.1 * log(32.0) + 1.0;
  ctab[idx] = (float)(cos(ang) * conc);
  stab[idx] = (float)(sin(ang) * conc);
}

// ---------------- RMSNorm fp32 -> bf16 (vectorized) ----------------
__global__ __launch_bounds__(256) void rmsnorm_kernel(
    const float* __restrict__ x, const float* __restrict__ scale,
    unsigned short* __restrict__ t) {
  int row = blockIdx.x;
  const float4* xr = (const float4*)(x + (size_t)row * HID);
  const float4* sc = (const float4*)scale;
  float ss = 0.f;
  for (int c = threadIdx.x; c < HID / 4; c += 256) {
    float4 v = xr[c];
    ss += v.x * v.x + v.y * v.y + v.z * v.z + v.w * v.w;
  }
  #pragma unroll
  for (int m = 1; m < 64; m <<= 1) ss += __shfl_xor(ss, m);
  __shared__ float red[4];
  if ((threadIdx.x & 63) == 0) red[threadIdx.x >> 6] = ss;
  __syncthreads();
  float tot = red[0] + red[1] + red[2] + red[3];
  float rs = rsqrtf(tot / (float)HID + 1e-5f);
  for (int c = threadIdx.x; c < HID / 4; c += 256) {
    float4 v = xr[c];
    float4 s4 = sc[c];
    ushort4 o;
    o.x = f2bf(v.x * rs * s4.x); o.y = f2bf(v.y * rs * s4.y);
    o.z = f2bf(v.z * rs * s4.z); o.w = f2bf(v.w * rs * s4.w);
    *(ushort4*)&t[(size_t)row * HID + c * 4] = o;
  }
}

// ---------------- Weight fp32 -> bf16 ----------------
__global__ __launch_bounds__(256) void cvt_w_kernel(
    const float* __restrict__ w, unsigned short* __restrict__ wb, long total4) {
  long idx = (long)blockIdx.x * 256 + threadIdx.x;
  if (idx >= total4) return;
  long base = idx * 4;
  float4 v = *(const float4*)&w[base];
  ushort4 o;
  o.x = f2bf(v.x); o.y = f2bf(v.y); o.z = f2bf(v.z); o.w = f2bf(v.w);
  *(ushort4*)&wb[base] = o;
}

// ---------------- Phase-split pipelined GEMM, 1 block/CU ----------------
// C[M,NC] = A[M,K]bf16 @ B[NC,K]bf16^T (+bias, +resid)
// BM=128, BN in {320,192}; BK=64; 512 thr = 8 waves (2M x 4N); dbuf LDS + T2 swizzle.
template<int BN, bool RESID>
__global__ __launch_bounds__(512, 2) void gemm8p_kernel(
    const unsigned short* __restrict__ A, const unsigned short* __restrict__ B,
    const float* __restrict__ bias, const float* __restrict__ resid,
    void* __restrict__ Cout, int K, int NC) {
  constexpr int NF  = BN / 64;        // N-frags per wave (5 or 3)
  constexpr int NB  = BN / 64;        // B slices (64 rows each)
  constexpr int NFL = (NF + 1) / 2;   // frags in phase-half 0
  __shared__ unsigned short sA[2][8192];       // 128x64 per buf
  __shared__ unsigned short sB[2][BN * 64];

  const int tid = threadIdx.x;
  // XCD-aware swizzle (grid % 8 == 0 for both launches)
  const int q8 = gridDim.x >> 3;
  const int sw = ((int)blockIdx.x & 7) * q8 + ((int)blockIdx.x >> 3);
  const int m0 = (sw & 15) * 128;
  const int n0 = (sw >> 4) * BN;

  const int lane = tid & 63, wid = tid >> 6;
  const int fr = lane & 15, fq = lane >> 4;
  const int wr = wid >> 2, wc = wid & 3;
  const int swz = (fr & 12) << 3;                    // read-side XOR (byte bits 5,6)
  const int r_st = tid >> 3;
  const int c8_st = ((tid & 7) ^ ((tid >> 4) & 6)) * 8;  // pre-swizzled source chunk
  const int wlds = wid << 9;                         // wave's 1KB chunk (ushort units)

  const unsigned short* Ag = A + (size_t)(m0 + r_st) * K + c8_st;
  const unsigned short* Bg = B + (size_t)(n0 + r_st) * K + c8_st;

  f32x4 acc[4][NF] = {};
  const int NT = K >> 6;

  auto LDA_ = [&](int bs, int mf, int ks) -> short8 {
    int row = wr * 64 + mf * 16 + fr;
    int cb = (ks * 64 + fq * 16) ^ swz;
    return *(const short8*)((const char*)&sA[bs][0] + row * 128 + cb);
  };
  auto LDB_ = [&](int bs, int nf, int ks) -> short8 {
    int row = wc * (NF * 16) + nf * 16 + fr;
    int cb = (ks * 64 + fq * 16) ^ swz;
    return *(const short8*)((const char*)&sB[bs][0] + row * 128 + cb);
  };

  // -------- prologue: stage tile 0 fully
  gload_lds16(Ag, &sA[0][wlds]);
  gload_lds16(Ag + (size_t)64 * K, &sA[0][4096 + wlds]);
  #pragma unroll
  for (int s = 0; s < NB; ++s)
    gload_lds16(Bg + (size_t)(s * 64) * K, &sB[0][s * 4096 + wlds]);
  asm volatile("s_waitcnt vmcnt(0)" ::: "memory");
  __builtin_amdgcn_s_barrier();

  short8 afr[4];
  short8 bfr[NF];

  for (int t = 0; t < NT; ++t) {
    const int cu = t & 1;
    const bool pf = (t + 1 < NT);
    const unsigned short* Agt = Ag + (t + 1) * 64;
    const unsigned short* Bgt = Bg + (t + 1) * 64;

    // ---- phase 0: ks=0, frags [0,NFL); stage B slices 0..NB-3 of t+1
    #pragma unroll
    for (int mf = 0; mf < 4; ++mf) afr[mf] = LDA_(cu, mf, 0);
    #pragma unroll
    for (int nf = 0; nf < NFL; ++nf) bfr[nf] = LDB_(cu, nf, 0);
    if (pf) {
      #pragma unroll
      for (int s = 0; s < NB - 2; ++s)
        gload_lds16(Bgt + (size_t)(s * 64) * K, &sB[cu ^ 1][s * 4096 + wlds]);
    }
    __builtin_amdgcn_s_barrier();
    asm volatile("s_waitcnt lgkmcnt(0)" ::: "memory");
    __builtin_amdgcn_sched_barrier(0);
    __builtin_amdgcn_s_setprio(1);
    #pragma unroll
    for (int mf = 0; mf < 4; ++mf)
      #pragma unroll
      for (int nf = 0; nf < NFL; ++nf)
        acc[mf][nf] = __builtin_amdgcn_mfma_f32_16x16x32_bf16(afr[mf], bfr[nf], acc[mf][nf], 0, 0, 0);
    __builtin_amdgcn_s_setprio(0);
    __builtin_amdgcn_s_barrier();

    // ---- phase 1: ks=0, frags [NFL,NF); stage B slices NB-2, NB-1
    #pragma unroll
    for (int nf = NFL; nf < NF; ++nf) bfr[nf] = LDB_(cu, nf, 0);
    if (pf) {
      gload_lds16(Bgt + (size_t)((NB - 2) * 64) * K, &sB[cu ^ 1][(NB - 2) * 4096 + wlds]);
      gload_lds16(Bgt + (size_t)((NB - 1) * 64) * K, &sB[cu ^ 1][(NB - 1) * 4096 + wlds]);
    }
    __builtin_amdgcn_s_barrier();
    asm volatile("s_waitcnt lgkmcnt(0)" ::: "memory");
    __builtin_amdgcn_sched_barrier(0);
    __builtin_amdgcn_s_setprio(1);
    #pragma unroll
    for (int mf = 0; mf < 4; ++mf)
      #pragma unroll
      for (int nf = NFL; nf < NF; ++nf)
        acc[mf][nf] = __builtin_amdgcn_mfma_f32_16x16x32_bf16(afr[mf], bfr[nf], acc[mf][nf], 0, 0, 0);
    __builtin_amdgcn_s_setprio(0);
    __builtin_amdgcn_s_barrier();

    // ---- phase 2: ks=1, frags [0,NFL); stage A slices 0,1
    #pragma unroll
    for (int mf = 0; mf < 4; ++mf) afr[mf] = LDA_(cu, mf, 1);
    #pragma unroll
    for (int nf = 0; nf < NFL; ++nf) bfr[nf] = LDB_(cu, nf, 1);
    if (pf) {
      gload_lds16(Agt, &sA[cu ^ 1][wlds]);
      gload_lds16(Agt + (size_t)64 * K, &sA[cu ^ 1][4096 + wlds]);
    }
    __builtin_amdgcn_s_barrier();
    asm volatile("s_waitcnt lgkmcnt(0)" ::: "memory");
    __builtin_amdgcn_sched_barrier(0);
    __builtin_amdgcn_s_setprio(1);
    #pragma unroll
    for (int mf = 0; mf < 4; ++mf)
      #pragma unroll
      for (int nf = 0; nf < NFL; ++nf)
        acc[mf][nf] = __builtin_amdgcn_mfma_f32_16x16x32_bf16(afr[mf], bfr[nf], acc[mf][nf], 0, 0, 0);
    __builtin_amdgcn_s_setprio(0);
    __builtin_amdgcn_s_barrier();

    // ---- phase 3: ks=1, frags [NFL,NF); drain (>=1 phase slack on newest loads)
    #pragma unroll
    for (int nf = NFL; nf < NF; ++nf) bfr[nf] = LDB_(cu, nf, 1);
    asm volatile("s_waitcnt vmcnt(0)" ::: "memory");
    __builtin_amdgcn_s_barrier();
    asm volatile("s_waitcnt lgkmcnt(0)" ::: "memory");
    __builtin_amdgcn_sched_barrier(0);
    __builtin_amdgcn_s_setprio(1);
    #pragma unroll
    for (int mf = 0; mf < 4; ++mf)
      #pragma unroll
      for (int nf = NFL; nf < NF; ++nf)
        acc[mf][nf] = __builtin_amdgcn_mfma_f32_16x16x32_bf16(afr[mf], bfr[nf], acc[mf][nf], 0, 0, 0);
    __builtin_amdgcn_s_setprio(0);
    __builtin_amdgcn_s_barrier();
  }

  // -------- epilogue
  if (!RESID) {
    unsigned short* C = (unsigned short*)Cout;
    #pragma unroll
    for (int mf = 0; mf < 4; ++mf)
      #pragma unroll
      for (int nf = 0; nf < NF; ++nf)
        #pragma unroll
        for (int r = 0; r < 4; ++r) {
          int row = m0 + wr * 64 + mf * 16 + fq * 4 + r;
          int col = n0 + wc * (NF * 16) + nf * 16 + fr;
          C[(size_t)row * NC + col] = f2bf(acc[mf][nf][r] + bias[col]);
        }
  } else {
    float* C = (float*)Cout;
    #pragma unroll
    for (int mf = 0; mf < 4; ++mf)
      #pragma unroll
      for (int nf = 0; nf < NF; ++nf)
        #pragma unroll
        for (int r = 0; r < 4; ++r) {
          int row = m0 + wr * 64 + mf * 16 + fq * 4 + r;
          int col = n0 + wc * (NF * 16) + nf * 16 + fr;
          C[(size_t)row * NC + col] = acc[mf][nf][r] + bias[col] + resid[(size_t)row * NC + col];
        }
  }
}

// ---------------- MFMA sliding-window attention with sinks + fused RoPE ----------------
__global__ __launch_bounds__(256) void attn_kernel(
    const unsigned short* __restrict__ qkv, const float* __restrict__ sinks,
    const float* __restrict__ ctab, const float* __restrict__ stab,
    unsigned short* __restrict__ attn) {
  const int tile = blockIdx.x;
  const int gh = blockIdx.y;
  const int h = gh >> 3;
  const int q0 = tile * 64;
  const int kbase = q0 - 127;

  __shared__ unsigned short Qsh[64][72];
  __shared__ unsigned short Ksh[192][72];
  __shared__ unsigned short Vt[64][200];    // transposed V: [dim][key]
  __shared__ float rowpart[4][64];
  __shared__ float invsum[64];
  unsigned short (*Wsh)[200] = (unsigned short (*)[200])Ksh;  // overlay after scores

  const int tid = threadIdx.x;

  // ---- stage Q with RoPE: thread = (row, chunk-pair)
  {
    int r = tid >> 2, cp = tid & 3;
    int i = q0 + r;
    const unsigned short* qp = &qkv[(size_t)i * QKVD + gh * 64 + cp * 8];
    short8 xa = *(const short8*)qp;
    short8 xb = *(const short8*)(qp + 32);
    short8 oa, ob;
    #pragma unroll
    for (int e = 0; e < 8; ++e) {
      float c = ctab[i * 32 + cp * 8 + e], s = stab[i * 32 + cp * 8 + e];
      float x1 = bf2f((unsigned short)xa[e]), x2 = bf2f((unsigned short)xb[e]);
      oa[e] = (short)f2bf(x1 * c - x2 * s);
      ob[e] = (short)f2bf(x2 * c + x1 * s);
    }
    *(short8*)&Qsh[r][cp * 8] = oa;
    *(short8*)&Qsh[r][cp * 8 + 32] = ob;
  }
  // ---- stage K with RoPE, zero-fill out-of-range
  #pragma unroll
  for (int it = 0; it < 3; ++it) {
    int lin = tid + it * 256;
    int r = lin >> 2, cp = lin & 3;
    int j = kbase + r;
    short8 oa = {}, ob = {};
    if (j >= 0 && j < NTOK) {
      const unsigned short* kp = &qkv[(size_t)j * QKVD + KOFF + h * 64 + cp * 8];
      short8 xa = *(const short8*)kp;
      short8 xb = *(const short8*)(kp + 32);
      #pragma unroll
      for (int e = 0; e < 8; ++e) {
        float c = ctab[j * 32 + cp * 8 + e], s = stab[j * 32 + cp * 8 + e];
        float x1 = bf2f((unsigned short)xa[e]), x2 = bf2f((unsigned short)xb[e]);
        oa[e] = (short)f2bf(x1 * c - x2 * s);
        ob[e] = (short)f2bf(x2 * c + x1 * s);
      }
    }
    *(short8*)&Ksh[r][cp * 8] = oa;
    *(short8*)&Ksh[r][cp * 8 + 32] = ob;
  }
  // ---- stage V transposed
  #pragma unroll
  for (int c = 0; c < 6; ++c) {
    int lin = tid + c * 256;
    int r = lin >> 3, ch = (lin & 7) * 8;
    int j = kbase + r;
    uint4 v = make_uint4(0u, 0u, 0u, 0u);
    if (j >= 0 && j < NTOK) v = *(const uint4*)&qkv[(size_t)j * QKVD + VOFF + h * 64 + ch];
    const unsigned short* vs = (const unsigned short*)&v;
    #pragma unroll
    for (int i2 = 0; i2 < 8; ++i2) Vt[ch + i2][r] = vs[i2];
  }
  __syncthreads();

  const int lane = tid & 63;
  const int wid = tid >> 6;
  const int fr = lane & 15;
  const int fq = lane >> 4;
  const int fc = fq * 8;
  const int wk0 = wid * 48;     // this wave's 48-key range

  // ---- scores: S[64][48] per wave
  f32x4 sc[4][3] = {};
  #pragma unroll
  for (int k0 = 0; k0 < 64; k0 += 32) {
    short8 qa[4], kb[3];
    #pragma unroll
    for (int mi = 0; mi < 4; ++mi) qa[mi] = *(const short8*)&Qsh[mi * 16 + fr][k0 + fc];
    #pragma unroll
    for (int ni = 0; ni < 3; ++ni) kb[ni] = *(const short8*)&Ksh[wk0 + ni * 16 + fr][k0 + fc];
    #pragma unroll
    for (int mi = 0; mi < 4; ++mi)
      #pragma unroll
      for (int ni = 0; ni < 3; ++ni)
        sc[mi][ni] = __builtin_amdgcn_mfma_f32_16x16x32_bf16(qa[mi], kb[ni], sc[mi][ni], 0, 0, 0);
  }

  // ---- mask + exp in-register; per-row partial sums
  float rsum[4][4];
  #pragma unroll
  for (int mi = 0; mi < 4; ++mi)
    #pragma unroll
    for (int r = 0; r < 4; ++r) {
      int i = q0 + mi * 16 + fq * 4 + r;
      float rs = 0.f;
      #pragma unroll
      for (int ni = 0; ni < 3; ++ni) {
        int kk = wk0 + ni * 16 + fr;
        int j = kbase + kk;
        bool valid = (j >= 0) && (j <= i) && (j > i - 128);
        float pw = valid ? __expf(sc[mi][ni][r] * 0.125f) : 0.f;
        sc[mi][ni][r] = pw;
        rs += pw;
      }
      rs += __shfl_xor(rs, 1);
      rs += __shfl_xor(rs, 2);
      rs += __shfl_xor(rs, 4);
      rs += __shfl_xor(rs, 8);
      rsum[mi][r] = rs;
    }

  __syncthreads();   // all Ksh reads complete; safe to overlay Wsh

  #pragma unroll
  for (int mi = 0; mi < 4; ++mi)
    #pragma unroll
    for (int r = 0; r < 4; ++r) {
      int row = mi * 16 + fq * 4 + r;
      #pragma unroll
      for (int ni = 0; ni < 3; ++ni)
        Wsh[row][wk0 + ni * 16 + fr] = f2bf(sc[mi][ni][r]);
      if (fr == 0) rowpart[wid][row] = rsum[mi][r];
    }
  __syncthreads();

  if (tid < 64) {
    float tot = rowpart[0][tid] + rowpart[1][tid] + rowpart[2][tid] + rowpart[3][tid];
    invsum[tid] = 1.f / (tot + __expf(sinks[gh]));
  }

  // ---- PV: out[64][16] per wave, K=192
  f32x4 pv[4] = {};
  #pragma unroll
  for (int k0 = 0; k0 < 192; k0 += 32) {
    short8 pa[4];
    #pragma unroll
    for (int mi = 0; mi < 4; ++mi) pa[mi] = *(const short8*)&Wsh[mi * 16 + fr][k0 + fc];
    short8 vb = *(const short8*)&Vt[wid * 16 + fr][k0 + fc];
    #pragma unroll
    for (int mi = 0; mi < 4; ++mi)
      pv[mi] = __builtin_amdgcn_mfma_f32_16x16x32_bf16(pa[mi], vb, pv[mi], 0, 0, 0);
  }
  __syncthreads();   // invsum visible

  #pragma unroll
  for (int mi = 0; mi < 4; ++mi)
    #pragma unroll
    for (int r = 0; r < 4; ++r) {
      int row = mi * 16 + fq * 4 + r;
      float inv = invsum[row];
      int col = wid * 16 + fr;
      attn[(size_t)(q0 + row) * ATTD + gh * 64 + col] = f2bf(pv[mi][r] * inv);
    }
}

extern "C" void kernel_launch(void* const* d_in, const int* in_sizes, int n_in,
                              void* d_out, int out_size, void* d_ws, size_t ws_size,
                              hipStream_t stream) {
  const float* x          = (const float*)d_in[0];
  const float* norm_scale = (const float*)d_in[1];
  const float* sinks      = (const float*)d_in[2];
  const float* w_qkv      = (const float*)d_in[3];
  const float* b_qkv      = (const float*)d_in[4];
  const float* w_out      = (const float*)d_in[5];
  const float* b_out      = (const float*)d_in[6];
  float* out = (float*)d_out;

  // workspace:
  //   [0, 21.0MB)     qkv_bf  (2048x5120 bf16, pre-RoPE)
  //   [21.0, 37.8MB)  t_bf (11.8MB, dead after gemm1) overlaid by attn_b (16.8MB)
  //   [37.8, 67.3MB)  wbf (w_qkv_bf 29.5MB, then w_out_bf 23.6MB)
  //   [67.3, 67.9MB)  ctab, stab
  char* ws = (char*)d_ws;
  unsigned short* qkv_bf = (unsigned short*)(ws);
  unsigned short* t_bf   = (unsigned short*)(ws + 20971520);
  unsigned short* attn_b = (unsigned short*)(ws + 20971520);
  unsigned short* wbf    = (unsigned short*)(ws + 20971520 + 16777216);
  float*          ctab   = (float*)(ws + 20971520 + 16777216 + 29491200);
  float*          stab   = ctab + NTOK * 32;

  rope_table_kernel<<<dim3(256), dim3(256), 0, stream>>>(ctab, stab);
  rmsnorm_kernel<<<dim3(NTOK), dim3(256), 0, stream>>>(x, norm_scale, t_bf);
  // w_qkv: 5120x2880 fp32 -> bf16
  cvt_w_kernel<<<dim3(14400), dim3(256), 0, stream>>>(w_qkv, wbf, 3686400L);
  // GEMM1: 2048x5120x2880, tiles 128x320 -> 16x16 = 256 blocks
  gemm8p_kernel<320, false><<<dim3(256), dim3(512), 0, stream>>>(
      t_bf, wbf, b_qkv, nullptr, (void*)qkv_bf, HID, QKVD);
  attn_kernel<<<dim3(32, 64), dim3(256), 0, stream>>>(qkv_bf, sinks, ctab, stab, attn_b);
  // w_out: 2880x4096 fp32 -> bf16 (no padding needed: 2880 = 15*192)
  cvt_w_kernel<<<dim3(11520), dim3(256), 0, stream>>>(w_out, wbf, 2949120L);
  // GEMM2: 2048x2880x4096, tiles 128x192 -> 16x15 = 240 blocks
  gemm8p_kernel<192, true><<<dim3(240), dim3(512), 0, stream>>>(
      attn_b, wbf, b_out, x, (void*)out, ATTD, HID);
}

// Round 5
// 235.647 us; speedup vs baseline: 2.7428x; 1.0598x over previous
//
#include <hip/hip_runtime.h>
#include <hip/hip_bf16.h>
#include <math.h>

typedef __attribute__((ext_vector_type(8))) short short8;
typedef __attribute__((ext_vector_type(4))) float f32x4;

#define NTOK 2048
#define HID  2880
#define QKVD 5120
#define KOFF 4096
#define VOFF 4608
#define ATTD 4096   // N_HEADS*HEAD_DIM

__device__ __forceinline__ unsigned short f2bf(float f) {
  union { float f; unsigned int u; } v; v.f = f;
  unsigned int u = v.u;
  unsigned int r = (u + 0x7FFFu + ((u >> 16) & 1u)) >> 16;
  return (unsigned short)r;
}
__device__ __forceinline__ float bf2f(unsigned short h) {
  union { unsigned int u; float f; } v; v.u = ((unsigned int)h) << 16; return v.f;
}
__device__ __forceinline__ void gload_lds16(const unsigned short* g, unsigned short* l) {
  __builtin_amdgcn_global_load_lds(
      (const __attribute__((address_space(1))) unsigned int*)g,
      (__attribute__((address_space(3))) unsigned int*)l, 16, 0, 0);
}

// ---------------- RoPE cos/sin table (YaRN) ----------------
__global__ void rope_table_kernel(float* __restrict__ ctab, float* __restrict__ stab) {
  int idx = blockIdx.x * 256 + threadIdx.x;
  if (idx >= NTOK * 32) return;
  int pos = idx >> 5, i = idx & 31;
  const double theta = 150000.0;
  const double two_pi = 6.283185307179586476925286766559;
  double freq = pow(theta, (double)i / 32.0);
  double interp = 1.0 / (32.0 * freq);
  double extrap = 1.0 / freq;
  double low  = 32.0 * log(4096.0 / (32.0 * two_pi)) / log(theta);
  double high = 32.0 * log(4096.0 / (1.0  * two_pi)) / log(theta);
  double ramp = ((double)i - low) / (high - low);
  ramp = ramp < 0.0 ? 0.0 : (ramp > 1.0 ? 1.0 : ramp);
  double maskv = 1.0 - ramp;
  double inv = interp * (1.0 - maskv) + extrap * maskv;
  double ang = (double)pos * inv;
  double conc = 0.1 * log(32.0) + 1.0;
  ctab[idx] = (float)(cos(ang) * conc);
  stab[idx] = (float)(sin(ang) * conc);
}

// ---------------- RMSNorm fp32 -> bf16 (vectorized) ----------------
__global__ __launch_bounds__(256) void rmsnorm_kernel(
    const float* __restrict__ x, const float* __restrict__ scale,
    unsigned short* __restrict__ t) {
  int row = blockIdx.x;
  const float4* xr = (const float4*)(x + (size_t)row * HID);
  const float4* sc = (const float4*)scale;
  float ss = 0.f;
  for (int c = threadIdx.x; c < HID / 4; c += 256) {
    float4 v = xr[c];
    ss += v.x * v.x + v.y * v.y + v.z * v.z + v.w * v.w;
  }
  #pragma unroll
  for (int m = 1; m < 64; m <<= 1) ss += __shfl_xor(ss, m);
  __shared__ float red[4];
  if ((threadIdx.x & 63) == 0) red[threadIdx.x >> 6] = ss;
  __syncthreads();
  float tot = red[0] + red[1] + red[2] + red[3];
  float rs = rsqrtf(tot / (float)HID + 1e-5f);
  for (int c = threadIdx.x; c < HID / 4; c += 256) {
    float4 v = xr[c];
    float4 s4 = sc[c];
    ushort4 o;
    o.x = f2bf(v.x * rs * s4.x); o.y = f2bf(v.y * rs * s4.y);
    o.z = f2bf(v.z * rs * s4.z); o.w = f2bf(v.w * rs * s4.w);
    *(ushort4*)&t[(size_t)row * HID + c * 4] = o;
  }
}

// ---------------- Weight fp32 -> bf16 ----------------
__global__ __launch_bounds__(256) void cvt_w_kernel(
    const float* __restrict__ w, unsigned short* __restrict__ wb, long total4) {
  long idx = (long)blockIdx.x * 256 + threadIdx.x;
  if (idx >= total4) return;
  long base = idx * 4;
  float4 v = *(const float4*)&w[base];
  ushort4 o;
  o.x = f2bf(v.x); o.y = f2bf(v.y); o.z = f2bf(v.z); o.w = f2bf(v.w);
  *(ushort4*)&wb[base] = o;
}

// ---------------- Pipelined GEMM, 1 block/CU, relaxed sync ----------------
// C[M,NC] = A[M,K]bf16 @ B[NC,K]bf16^T (+bias, +resid)
// BM=128, BN in {320,192}; BK=64; 512 thr = 8 waves (2M x 4N); dbuf LDS,
// 3-bit T2 swizzle (conflict-free), one barrier + one full-slack vmcnt(0)/tile.
template<int BN, bool RESID>
__global__ __launch_bounds__(512, 2) void gemm8p_kernel(
    const unsigned short* __restrict__ A, const unsigned short* __restrict__ B,
    const float* __restrict__ bias, const float* __restrict__ resid,
    void* __restrict__ Cout, int K, int NC) {
  constexpr int NF = BN / 64;         // N-frags per wave (5 or 3)
  constexpr int NB = BN / 64;         // B slices (64 rows each)
  __shared__ unsigned short sA[2][8192];       // 128x64 bf16 per buf
  __shared__ unsigned short sB[2][BN * 64];

  const int tid = threadIdx.x;
  // XCD-aware swizzle (grid % 8 == 0 for both launches)
  const int q8 = gridDim.x >> 3;
  const int sw = ((int)blockIdx.x & 7) * q8 + ((int)blockIdx.x >> 3);
  const int m0 = (sw & 15) * 128;
  const int n0 = (sw >> 4) * BN;

  const int lane = tid & 63, wid = tid >> 6;
  const int fr = lane & 15, fq = lane >> 4;
  const int wr = wid >> 2, wc = wid & 3;
  const int swz = (fr & 7) << 4;                     // read-side XOR (byte bits 4,5,6)
  const int r_st = tid >> 3;                         // staged row within 64-row slice
  const int c8_st = ((tid & 7) ^ ((tid >> 3) & 7)) * 8;  // inverse-swizzled source chunk
  const int wlds = wid << 9;                         // wave's 1KB chunk (ushort units)

  const unsigned short* Ag = A + (size_t)(m0 + r_st) * K + c8_st;
  const unsigned short* Bg = B + (size_t)(n0 + r_st) * K + c8_st;

  f32x4 acc[4][NF] = {};
  const int NT = K >> 6;

  auto LDA_ = [&](int bs, int mf, int ks) -> short8 {
    int row = wr * 64 + mf * 16 + fr;                // row&7 == fr&7
    int cb = (ks * 64 + fq * 16) ^ swz;
    return *(const short8*)((const char*)&sA[bs][0] + row * 128 + cb);
  };
  auto LDB_ = [&](int bs, int nf, int ks) -> short8 {
    int row = wc * (NF * 16) + nf * 16 + fr;         // row&7 == fr&7 (80,48,16 ≡ 0 mod 8)
    int cb = (ks * 64 + fq * 16) ^ swz;
    return *(const short8*)((const char*)&sB[bs][0] + row * 128 + cb);
  };

  // -------- prologue: stage tile 0 fully into buf 0
  gload_lds16(Ag, &sA[0][wlds]);
  gload_lds16(Ag + (size_t)64 * K, &sA[0][4096 + wlds]);
  #pragma unroll
  for (int s = 0; s < NB; ++s)
    gload_lds16(Bg + (size_t)(s * 64) * K, &sB[0][s * 4096 + wlds]);
  asm volatile("s_waitcnt vmcnt(0)" ::: "memory");
  __builtin_amdgcn_s_barrier();

  for (int t = 0; t < NT; ++t) {
    const int cu = t & 1;
    const int nx = cu ^ 1;
    // ---- issue ALL of tile t+1's staging up front (full-tile slack)
    if (t + 1 < NT) {
      const unsigned short* Agt = Ag + (size_t)(t + 1) * 64;
      const unsigned short* Bgt = Bg + (size_t)(t + 1) * 64;
      gload_lds16(Agt, &sA[nx][wlds]);
      gload_lds16(Agt + (size_t)64 * K, &sA[nx][4096 + wlds]);
      #pragma unroll
      for (int s = 0; s < NB; ++s)
        gload_lds16(Bgt + (size_t)(s * 64) * K, &sB[nx][s * 4096 + wlds]);
    }
    __builtin_amdgcn_sched_barrier(0);
    // ---- compute on buf cu; compiler emits fine-grained lgkmcnt
    #pragma unroll
    for (int ks = 0; ks < 2; ++ks) {
      short8 afr[4], bfr[NF];
      #pragma unroll
      for (int mf = 0; mf < 4; ++mf) afr[mf] = LDA_(cu, mf, ks);
      #pragma unroll
      for (int nf = 0; nf < NF; ++nf) bfr[nf] = LDB_(cu, nf, ks);
      __builtin_amdgcn_s_setprio(1);
      #pragma unroll
      for (int mf = 0; mf < 4; ++mf)
        #pragma unroll
        for (int nf = 0; nf < NF; ++nf)
          acc[mf][nf] = __builtin_amdgcn_mfma_f32_16x16x32_bf16(afr[mf], bfr[nf], acc[mf][nf], 0, 0, 0);
      __builtin_amdgcn_s_setprio(0);
    }
    // ---- tile end: next buf fully written, current buf fully consumed
    asm volatile("s_waitcnt vmcnt(0)" ::: "memory");
    __builtin_amdgcn_s_barrier();
  }

  // -------- epilogue
  if (!RESID) {
    unsigned short* C = (unsigned short*)Cout;
    #pragma unroll
    for (int mf = 0; mf < 4; ++mf)
      #pragma unroll
      for (int nf = 0; nf < NF; ++nf)
        #pragma unroll
        for (int r = 0; r < 4; ++r) {
          int row = m0 + wr * 64 + mf * 16 + fq * 4 + r;
          int col = n0 + wc * (NF * 16) + nf * 16 + fr;
          C[(size_t)row * NC + col] = f2bf(acc[mf][nf][r] + bias[col]);
        }
  } else {
    float* C = (float*)Cout;
    #pragma unroll
    for (int mf = 0; mf < 4; ++mf)
      #pragma unroll
      for (int nf = 0; nf < NF; ++nf)
        #pragma unroll
        for (int r = 0; r < 4; ++r) {
          int row = m0 + wr * 64 + mf * 16 + fq * 4 + r;
          int col = n0 + wc * (NF * 16) + nf * 16 + fr;
          C[(size_t)row * NC + col] = acc[mf][nf][r] + bias[col] + resid[(size_t)row * NC + col];
        }
  }
}

// ---------------- MFMA sliding-window attention with sinks + fused RoPE ----------------
__global__ __launch_bounds__(256) void attn_kernel(
    const unsigned short* __restrict__ qkv, const float* __restrict__ sinks,
    const float* __restrict__ ctab, const float* __restrict__ stab,
    unsigned short* __restrict__ attn) {
  const int tile = blockIdx.x;
  const int gh = blockIdx.y;
  const int h = gh >> 3;
  const int q0 = tile * 64;
  const int kbase = q0 - 127;

  __shared__ unsigned short Qsh[64][72];
  __shared__ unsigned short Ksh[192][72];
  __shared__ unsigned short Vt[64][200];    // transposed V: [dim][key]
  __shared__ float rowpart[4][64];
  __shared__ float invsum[64];
  unsigned short (*Wsh)[200] = (unsigned short (*)[200])Ksh;  // overlay after scores

  const int tid = threadIdx.x;

  // ---- stage Q with RoPE: thread = (row, chunk-pair)
  {
    int r = tid >> 2, cp = tid & 3;
    int i = q0 + r;
    const unsigned short* qp = &qkv[(size_t)i * QKVD + gh * 64 + cp * 8];
    short8 xa = *(const short8*)qp;
    short8 xb = *(const short8*)(qp + 32);
    short8 oa, ob;
    #pragma unroll
    for (int e = 0; e < 8; ++e) {
      float c = ctab[i * 32 + cp * 8 + e], s = stab[i * 32 + cp * 8 + e];
      float x1 = bf2f((unsigned short)xa[e]), x2 = bf2f((unsigned short)xb[e]);
      oa[e] = (short)f2bf(x1 * c - x2 * s);
      ob[e] = (short)f2bf(x2 * c + x1 * s);
    }
    *(short8*)&Qsh[r][cp * 8] = oa;
    *(short8*)&Qsh[r][cp * 8 + 32] = ob;
  }
  // ---- stage K with RoPE, zero-fill out-of-range
  #pragma unroll
  for (int it = 0; it < 3; ++it) {
    int lin = tid + it * 256;
    int r = lin >> 2, cp = lin & 3;
    int j = kbase + r;
    short8 oa = {}, ob = {};
    if (j >= 0 && j < NTOK) {
      const unsigned short* kp = &qkv[(size_t)j * QKVD + KOFF + h * 64 + cp * 8];
      short8 xa = *(const short8*)kp;
      short8 xb = *(const short8*)(kp + 32);
      #pragma unroll
      for (int e = 0; e < 8; ++e) {
        float c = ctab[j * 32 + cp * 8 + e], s = stab[j * 32 + cp * 8 + e];
        float x1 = bf2f((unsigned short)xa[e]), x2 = bf2f((unsigned short)xb[e]);
        oa[e] = (short)f2bf(x1 * c - x2 * s);
        ob[e] = (short)f2bf(x2 * c + x1 * s);
      }
    }
    *(short8*)&Ksh[r][cp * 8] = oa;
    *(short8*)&Ksh[r][cp * 8 + 32] = ob;
  }
  // ---- stage V transposed
  #pragma unroll
  for (int c = 0; c < 6; ++c) {
    int lin = tid + c * 256;
    int r = lin >> 3, ch = (lin & 7) * 8;
    int j = kbase + r;
    uint4 v = make_uint4(0u, 0u, 0u, 0u);
    if (j >= 0 && j < NTOK) v = *(const uint4*)&qkv[(size_t)j * QKVD + VOFF + h * 64 + ch];
    const unsigned short* vs = (const unsigned short*)&v;
    #pragma unroll
    for (int i2 = 0; i2 < 8; ++i2) Vt[ch + i2][r] = vs[i2];
  }
  __syncthreads();

  const int lane = tid & 63;
  const int wid = tid >> 6;
  const int fr = lane & 15;
  const int fq = lane >> 4;
  const int fc = fq * 8;
  const int wk0 = wid * 48;     // this wave's 48-key range

  // ---- scores: S[64][48] per wave
  f32x4 sc[4][3] = {};
  #pragma unroll
  for (int k0 = 0; k0 < 64; k0 += 32) {
    short8 qa[4], kb[3];
    #pragma unroll
    for (int mi = 0; mi < 4; ++mi) qa[mi] = *(const short8*)&Qsh[mi * 16 + fr][k0 + fc];
    #pragma unroll
    for (int ni = 0; ni < 3; ++ni) kb[ni] = *(const short8*)&Ksh[wk0 + ni * 16 + fr][k0 + fc];
    #pragma unroll
    for (int mi = 0; mi < 4; ++mi)
      #pragma unroll
      for (int ni = 0; ni < 3; ++ni)
        sc[mi][ni] = __builtin_amdgcn_mfma_f32_16x16x32_bf16(qa[mi], kb[ni], sc[mi][ni], 0, 0, 0);
  }

  // ---- mask + exp in-register; per-row partial sums
  float rsum[4][4];
  #pragma unroll
  for (int mi = 0; mi < 4; ++mi)
    #pragma unroll
    for (int r = 0; r < 4; ++r) {
      int i = q0 + mi * 16 + fq * 4 + r;
      float rs = 0.f;
      #pragma unroll
      for (int ni = 0; ni < 3; ++ni) {
        int kk = wk0 + ni * 16 + fr;
        int j = kbase + kk;
        bool valid = (j >= 0) && (j <= i) && (j > i - 128);
        float pw = valid ? __expf(sc[mi][ni][r] * 0.125f) : 0.f;
        sc[mi][ni][r] = pw;
        rs += pw;
      }
      rs += __shfl_xor(rs, 1);
      rs += __shfl_xor(rs, 2);
      rs += __shfl_xor(rs, 4);
      rs += __shfl_xor(rs, 8);
      rsum[mi][r] = rs;
    }

  __syncthreads();   // all Ksh reads complete; safe to overlay Wsh

  #pragma unroll
  for (int mi = 0; mi < 4; ++mi)
    #pragma unroll
    for (int r = 0; r < 4; ++r) {
      int row = mi * 16 + fq * 4 + r;
      #pragma unroll
      for (int ni = 0; ni < 3; ++ni)
        Wsh[row][wk0 + ni * 16 + fr] = f2bf(sc[mi][ni][r]);
      if (fr == 0) rowpart[wid][row] = rsum[mi][r];
    }
  __syncthreads();

  if (tid < 64) {
    float tot = rowpart[0][tid] + rowpart[1][tid] + rowpart[2][tid] + rowpart[3][tid];
    invsum[tid] = 1.f / (tot + __expf(sinks[gh]));
  }

  // ---- PV: out[64][16] per wave, K=192
  f32x4 pv[4] = {};
  #pragma unroll
  for (int k0 = 0; k0 < 192; k0 += 32) {
    short8 pa[4];
    #pragma unroll
    for (int mi = 0; mi < 4; ++mi) pa[mi] = *(const short8*)&Wsh[mi * 16 + fr][k0 + fc];
    short8 vb = *(const short8*)&Vt[wid * 16 + fr][k0 + fc];
    #pragma unroll
    for (int mi = 0; mi < 4; ++mi)
      pv[mi] = __builtin_amdgcn_mfma_f32_16x16x32_bf16(pa[mi], vb, pv[mi], 0, 0, 0);
  }
  __syncthreads();   // invsum visible

  #pragma unroll
  for (int mi = 0; mi < 4; ++mi)
    #pragma unroll
    for (int r = 0; r < 4; ++r) {
      int row = mi * 16 + fq * 4 + r;
      float inv = invsum[row];
      int col = wid * 16 + fr;
      attn[(size_t)(q0 + row) * ATTD + gh * 64 + col] = f2bf(pv[mi][r] * inv);
    }
}

extern "C" void kernel_launch(void* const* d_in, const int* in_sizes, int n_in,
                              void* d_out, int out_size, void* d_ws, size_t ws_size,
                              hipStream_t stream) {
  const float* x          = (const float*)d_in[0];
  const float* norm_scale = (const float*)d_in[1];
  const float* sinks      = (const float*)d_in[2];
  const float* w_qkv      = (const float*)d_in[3];
  const float* b_qkv      = (const float*)d_in[4];
  const float* w_out      = (const float*)d_in[5];
  const float* b_out      = (const float*)d_in[6];
  float* out = (float*)d_out;

  // workspace:
  //   [0, 21.0MB)     qkv_bf  (2048x5120 bf16, pre-RoPE)
  //   [21.0, 37.8MB)  t_bf (11.8MB, dead after gemm1) overlaid by attn_b (16.8MB)
  //   [37.8, 67.3MB)  wbf (w_qkv_bf 29.5MB, then w_out_bf 23.6MB)
  //   [67.3, 67.9MB)  ctab, stab
  char* ws = (char*)d_ws;
  unsigned short* qkv_bf = (unsigned short*)(ws);
  unsigned short* t_bf   = (unsigned short*)(ws + 20971520);
  unsigned short* attn_b = (unsigned short*)(ws + 20971520);
  unsigned short* wbf    = (unsigned short*)(ws + 20971520 + 16777216);
  float*          ctab   = (float*)(ws + 20971520 + 16777216 + 29491200);
  float*          stab   = ctab + NTOK * 32;

  rope_table_kernel<<<dim3(256), dim3(256), 0, stream>>>(ctab, stab);
  rmsnorm_kernel<<<dim3(NTOK), dim3(256), 0, stream>>>(x, norm_scale, t_bf);
  // w_qkv: 5120x2880 fp32 -> bf16
  cvt_w_kernel<<<dim3(14400), dim3(256), 0, stream>>>(w_qkv, wbf, 3686400L);
  // GEMM1: 2048x5120x2880, tiles 128x320 -> 16x16 = 256 blocks
  gemm8p_kernel<320, false><<<dim3(256), dim3(512), 0, stream>>>(
      t_bf, wbf, b_qkv, nullptr, (void*)qkv_bf, HID, QKVD);
  attn_kernel<<<dim3(32, 64), dim3(256), 0, stream>>>(qkv_bf, sinks, ctab, stab, attn_b);
  // w_out: 2880x4096 fp32 -> bf16 (no padding needed: 2880 = 15*192)
  cvt_w_kernel<<<dim3(11520), dim3(256), 0, stream>>>(w_out, wbf, 2949120L);
  // GEMM2: 2048x2880x4096, tiles 128x192 -> 16x15 = 240 blocks
  gemm8p_kernel<192, true><<<dim3(240), dim3(512), 0, stream>>>(
      attn_b, wbf, b_out, x, (void*)out, ATTD, HID);
}